// Round 1
// baseline (7694.859 us; speedup 1.0000x reference)
//
#include <hip/hip_runtime.h>
#include <hip/hip_fp16.h>
#include <stdint.h>

// LSTM-like scan, T=4096, E=1024, H=1024.
// Phase 1: xpre[t][g*1024+j] = x @ U_g^T + B_g   (fp32 tiled GEMM, stored fp16)
// Phase 2: persistent 32-WG kernel, weights in VGPRs (fp16), h broadcast via
//          tagged dwords ((epoch<<16)|fp16) with agent-scope relaxed atomics.

#define T_STEPS 4096
#define HDIM 1024

typedef _Float16 half2v __attribute__((ext_vector_type(2)));

__device__ __forceinline__ float dot2(uint32_t a, uint32_t b, float c) {
#if __has_builtin(__builtin_amdgcn_fdot2)
  return __builtin_amdgcn_fdot2(__builtin_bit_cast(half2v, a),
                                __builtin_bit_cast(half2v, b), c, false);
#else
  half2v av = __builtin_bit_cast(half2v, a);
  half2v bv = __builtin_bit_cast(half2v, b);
  return c + (float)av.x * (float)bv.x + (float)av.y * (float)bv.y;
#endif
}

// ---------------- weight conversion: 4x [1024][1024] f32 -> f16 ----------------
__global__ __launch_bounds__(256) void convw(const float* __restrict__ w0,
                                             const float* __restrict__ w1,
                                             const float* __restrict__ w2,
                                             const float* __restrict__ w3,
                                             __half* __restrict__ dst) {
  int i = (blockIdx.x * 256 + threadIdx.x) * 4;  // 0 .. 4M-4
  int g = i >> 20;
  int off = i & 1048575;
  const float* src = g == 0 ? w0 : g == 1 ? w1 : g == 2 ? w2 : w3;
  float4 v = *(const float4*)(src + off);
  union { __half h[4]; uint2 u; } cv;
  cv.h[0] = __float2half(v.x); cv.h[1] = __float2half(v.y);
  cv.h[2] = __float2half(v.z); cv.h[3] = __float2half(v.w);
  *(uint2*)(dst + i) = cv.u;
}

// ---------------- zero the tagged h broadcast buffers (2 x 1024 dwords) --------
__global__ void zerok(uint32_t* __restrict__ p) {
  int i = blockIdx.x * 256 + threadIdx.x;
  if (i < 2048) p[i] = 0;
}

// ---------------- fp32 GEMM: C[t][n] = x[t][:] . U_g[j][:] + B_g[j] ------------
// n = g*1024 + j ; column tiles never straddle gates (64 | 1024).
__global__ __launch_bounds__(256) void gemmk(
    const float* __restrict__ x,
    const float* __restrict__ u0, const float* __restrict__ u1,
    const float* __restrict__ u2, const float* __restrict__ u3,
    const float* __restrict__ b0, const float* __restrict__ b1,
    const float* __restrict__ b2, const float* __restrict__ b3,
    __half* __restrict__ xpre) {
  __shared__ float As[64][33];
  __shared__ float Bs[64][33];
  const int tid = threadIdx.x;
  const int m0 = blockIdx.y * 64;
  const int n0 = blockIdx.x * 64;
  const int g = n0 >> 10;
  const float* Up = g == 0 ? u0 : g == 1 ? u1 : g == 2 ? u2 : u3;
  const float* Bp = g == 0 ? b0 : g == 1 ? b1 : g == 2 ? b2 : b3;
  const int j0 = n0 & 1023;
  const int tx = tid & 15, ty = tid >> 4;
  const int lr = tid >> 3, lc = (tid & 7) << 2;
  float acc[4][4] = {};
  for (int k0 = 0; k0 < 1024; k0 += 32) {
    float4 a0 = *(const float4*)&x[(size_t)(m0 + lr) * 1024 + k0 + lc];
    float4 a1 = *(const float4*)&x[(size_t)(m0 + lr + 32) * 1024 + k0 + lc];
    float4 c0 = *(const float4*)&Up[(size_t)(j0 + lr) * 1024 + k0 + lc];
    float4 c1 = *(const float4*)&Up[(size_t)(j0 + lr + 32) * 1024 + k0 + lc];
    __syncthreads();
    As[lr][lc + 0] = a0.x; As[lr][lc + 1] = a0.y; As[lr][lc + 2] = a0.z; As[lr][lc + 3] = a0.w;
    As[lr + 32][lc + 0] = a1.x; As[lr + 32][lc + 1] = a1.y; As[lr + 32][lc + 2] = a1.z; As[lr + 32][lc + 3] = a1.w;
    Bs[lr][lc + 0] = c0.x; Bs[lr][lc + 1] = c0.y; Bs[lr][lc + 2] = c0.z; Bs[lr][lc + 3] = c0.w;
    Bs[lr + 32][lc + 0] = c1.x; Bs[lr + 32][lc + 1] = c1.y; Bs[lr + 32][lc + 2] = c1.z; Bs[lr + 32][lc + 3] = c1.w;
    __syncthreads();
#pragma unroll
    for (int k = 0; k < 32; ++k) {
      float a0v = As[ty * 4 + 0][k], a1v = As[ty * 4 + 1][k];
      float a2v = As[ty * 4 + 2][k], a3v = As[ty * 4 + 3][k];
      float b0v = Bs[tx * 4 + 0][k], b1v = Bs[tx * 4 + 1][k];
      float b2v = Bs[tx * 4 + 2][k], b3v = Bs[tx * 4 + 3][k];
      acc[0][0] += a0v * b0v; acc[0][1] += a0v * b1v; acc[0][2] += a0v * b2v; acc[0][3] += a0v * b3v;
      acc[1][0] += a1v * b0v; acc[1][1] += a1v * b1v; acc[1][2] += a1v * b2v; acc[1][3] += a1v * b3v;
      acc[2][0] += a2v * b0v; acc[2][1] += a2v * b1v; acc[2][2] += a2v * b2v; acc[2][3] += a2v * b3v;
      acc[3][0] += a3v * b0v; acc[3][1] += a3v * b1v; acc[3][2] += a3v * b2v; acc[3][3] += a3v * b3v;
    }
  }
#pragma unroll
  for (int i = 0; i < 4; ++i) {
    size_t rowi = (size_t)(m0 + ty * 4 + i);
#pragma unroll
    for (int j = 0; j < 4; ++j) {
      int jj = j0 + tx * 4 + j;
      float v = acc[i][j] + Bp[jj];
      xpre[rowi * 4096 + n0 + tx * 4 + j] = __float2half(v);
    }
  }
}

// ---------------- persistent recurrence kernel --------------------------------
// 32 WGs x 512 threads. WG i owns rows i*32..i*32+31 for all 4 gates.
// wave w: gate = w>>1, rows (w&1)*16 + lane/4 ; lane%4 = k-chunk of 256.
// Weights: 256 fp16 per lane, resident in 32x uint4 VGPRs.
// h broadcast: tagged[par][row] = ((t+1)<<16) | fp16(h), agent-scope atomics.
__global__ __launch_bounds__(512, 2) void rnnk(
    const __half* __restrict__ w16,   // [4][1024][1024] fp16
    const __half* __restrict__ xpre,  // [4096][4096] fp16
    uint32_t* tagged,                 // [2][1024] tagged h dwords
    float* __restrict__ out) {        // [4096][1024] f32
  __shared__ uint32_t hl[4 * 136];    // h pairs, 4 regions of 128 dwords, +8 pad to split banks
  __shared__ float gl[128];           // sigmoid(gate) values: [gate][32 rows]
  const int wg = blockIdx.x;
  const int tid = threadIdx.x;
  const int wave = tid >> 6, lane = tid & 63;
  const int g = wave >> 1;
  const int rloc = ((wave & 1) << 4) + (lane >> 2);  // 0..31
  const int row = (wg << 5) + rloc;                  // 0..1023
  const int c = lane & 3;                            // k-chunk
  const bool rowlead = (c == 0);
  const bool w0 = (wave == 0);

  // load this lane's 256 weights (512B) into registers
  uint4 wreg[32];
  {
    const uint4* wp = reinterpret_cast<const uint4*>(
        w16 + ((size_t)g << 20) + ((size_t)row << 10) + (c << 8));
#pragma unroll
    for (int i = 0; i < 32; ++i) wreg[i] = wp[i];
  }

  float s = 0.f;  // cell state, wave0 lanes<32 only

  for (int t = 0; t < T_STEPS; ++t) {
    // xpre prefetch (independent of the h exchange)
    float xv = 0.f;
    if (rowlead)
      xv = __half2float(xpre[(size_t)t * 4096 + ((size_t)g << 10) + row]);

    // --- acquire h_{t-1}: poll own pair of tagged dwords until tag == t ---
    {
      const unsigned long long* pp =
          reinterpret_cast<const unsigned long long*>(tagged + ((t & 1) << 10)) + tid;
      const uint32_t tg = (uint32_t)t;
      unsigned long long v =
          __hip_atomic_load(pp, __ATOMIC_RELAXED, __HIP_MEMORY_SCOPE_AGENT);
      while ((((uint32_t)(v >> 16) & 0xffffu) != tg) ||
             (((uint32_t)(v >> 48) & 0xffffu) != tg)) {
        __builtin_amdgcn_s_sleep(1);
        v = __hip_atomic_load(pp, __ATOMIC_RELAXED, __HIP_MEMORY_SCOPE_AGENT);
      }
      uint32_t pair = (uint32_t)(v & 0xffffu) | (((uint32_t)(v >> 32) & 0xffffu) << 16);
      hl[(tid >> 7) * 136 + (tid & 127)] = pair;
    }
    __syncthreads();  // hl ready

    // --- 256-MAC partial dot in fp16 pairs ---
    float p = 0.f;
    const uint4* hp = reinterpret_cast<const uint4*>(&hl[c * 136]);
#pragma unroll
    for (int i = 0; i < 32; ++i) {
      uint4 h4 = hp[i];
      p = dot2(wreg[i].x, h4.x, p);
      p = dot2(wreg[i].y, h4.y, p);
      p = dot2(wreg[i].z, h4.z, p);
      p = dot2(wreg[i].w, h4.w, p);
    }
    p += __shfl_xor(p, 1);
    p += __shfl_xor(p, 2);  // all 4 lanes of the row hold the full dot

    if (rowlead) {
      float z = p + xv;
      gl[(g << 5) + rloc] = 1.f / (1.f + __expf(-z));
    }
    __syncthreads();  // gl ready

    // --- epilogue: wave0 lanes 0..31 combine gates, update s, publish h ---
    if (w0 && lane < 32) {
      const int r = lane;
      float f = gl[r], cc = gl[32 + r], gg = gl[64 + r], q = gl[96 + r];
      s = f * s + gg * cc;
      float e2 = __expf(2.f * s);          // s >= 0 always; inf -> th = 1
      float th = 1.f - 2.f / (e2 + 1.f);
      float h = th * q;
      out[(size_t)t * HDIM + (wg << 5) + r] = h;
      uint32_t hb = (uint32_t)__half_as_ushort(__float2half(h));
      uint32_t dw = ((uint32_t)(t + 1) << 16) | hb;
      __hip_atomic_store(&tagged[(((t + 1) & 1) << 10) + (wg << 5) + r], dw,
                         __ATOMIC_RELAXED, __HIP_MEMORY_SCOPE_AGENT);
    }
    // no trailing barrier needed: next-epoch LDS writes are gated by the poll,
    // which can only succeed after every WG's wave0 published tag t+1.
  }
}

extern "C" void kernel_launch(void* const* d_in, const int* in_sizes, int n_in,
                              void* d_out, int out_size, void* d_ws, size_t ws_size,
                              hipStream_t stream) {
  const float* x  = (const float*)d_in[0];
  const float* Uf = (const float*)d_in[1];
  const float* Wf = (const float*)d_in[2];
  const float* Bf = (const float*)d_in[3];
  const float* Ug = (const float*)d_in[4];
  const float* Wg = (const float*)d_in[5];
  const float* Bg = (const float*)d_in[6];
  const float* Uq = (const float*)d_in[7];
  const float* Wq = (const float*)d_in[8];
  const float* Bq = (const float*)d_in[9];
  const float* U  = (const float*)d_in[10];
  const float* W  = (const float*)d_in[11];
  const float* B  = (const float*)d_in[12];
  float* out = (float*)d_out;

  // ws layout: [0,32MB) xpre fp16 [4096][4096]; [32MB,40MB) w16 fp16 [4][1024][1024];
  // [40MB, +8KB) tagged h dwords [2][1024]. Total ~40.01 MB.
  char* ws = (char*)d_ws;
  __half* xpre = (__half*)ws;
  __half* w16 = (__half*)(ws + (size_t)32 * 1024 * 1024);
  uint32_t* tagged = (uint32_t*)(ws + (size_t)40 * 1024 * 1024);

  // gate order everywhere: 0=f(Uf,Wf,Bf) 1=c(U,W,B) 2=g(Ug,Wg,Bg) 3=q(Uq,Wq,Bq)
  convw<<<4096, 256, 0, stream>>>(Wf, W, Wg, Wq, w16);
  zerok<<<8, 256, 0, stream>>>(tagged);
  gemmk<<<dim3(64, 64), 256, 0, stream>>>(x, Uf, U, Ug, Uq, Bf, B, Bg, Bq, xpre);
  rnnk<<<32, 512, 0, stream>>>(w16, xpre, tagged, out);
}